// Round 9
// baseline (762.498 us; speedup 1.0000x reference)
//
#include <hip/hip_runtime.h>
#include <hip/hip_fp16.h>
#include <math.h>
#include <stdint.h>

#define DD 64
#define CHUNK 1024
#define BKT 64          // nodes per bucket

using f16x8 = __attribute__((ext_vector_type(8))) _Float16;
using f32x4 = __attribute__((ext_vector_type(4))) float;

static inline int divup(int a, int b){ return (a + b - 1) / b; }

// --- B1: append edges into col-buckets (packed row<<6|c&63) and row ids into
//     row-buckets. Returning atomics hit only 2*nbkt hot cursor words ->
//     dirty-sector RMW traffic collapses vs the 800KB-footprint histogram. ---
__device__ __forceinline__ void bucket_one(int r, int c, int* bcur_c, int* bcur_r,
                                           unsigned int* colbuf, uint8_t* rowbuf, int cap){
  int pc = atomicAdd(&bcur_c[c >> 6], 1);
  if (pc < cap) colbuf[(size_t)(c >> 6) * cap + pc] = ((unsigned int)r << 6) | (unsigned int)(c & 63);
  int pr = atomicAdd(&bcur_r[r >> 6], 1);
  if (pr < cap) rowbuf[(size_t)(r >> 6) * cap + pr] = (uint8_t)(r & 63);
}

__global__ void bucket1v_k(const int* __restrict__ edg, int* __restrict__ bcur_c,
                           int* __restrict__ bcur_r, unsigned int* __restrict__ colbuf,
                           uint8_t* __restrict__ rowbuf, int cap, int E4){
  int i = blockIdx.x * 256 + threadIdx.x;
  if (i >= E4) return;
  int4 r4 = ((const int4*)edg)[i];
  int4 c4 = ((const int4*)edg)[E4 + i];
  bucket_one(r4.x, c4.x, bcur_c, bcur_r, colbuf, rowbuf, cap);
  bucket_one(r4.y, c4.y, bcur_c, bcur_r, colbuf, rowbuf, cap);
  bucket_one(r4.z, c4.z, bcur_c, bcur_r, colbuf, rowbuf, cap);
  bucket_one(r4.w, c4.w, bcur_c, bcur_r, colbuf, rowbuf, cap);
}

__global__ void bucket1s_k(const int* __restrict__ edg, int* __restrict__ bcur_c,
                           int* __restrict__ bcur_r, unsigned int* __restrict__ colbuf,
                           uint8_t* __restrict__ rowbuf, int cap, int E){
  int e = blockIdx.x * 256 + threadIdx.x;
  if (e < E) bucket_one(edg[e], edg[E + e], bcur_c, bcur_r, colbuf, rowbuf, cap);
}

// --- per-bucket LDS histogram of col entries -> colcnt ---
__global__ void bhistc_k(const unsigned int* __restrict__ colbuf, const int* __restrict__ bcur,
                         int cap, int* __restrict__ colcnt, int N){
  __shared__ int lh[BKT];
  int b = blockIdx.x, t = threadIdx.x;
  if (t < BKT) lh[t] = 0;
  __syncthreads();
  int cnt = bcur[b]; if (cnt > cap) cnt = cap;
  const unsigned int* buf = colbuf + (size_t)b * cap;
  for (int i = t; i < cnt; i += 256) atomicAdd(&lh[buf[i] & 63], 1);
  __syncthreads();
  int node = b * BKT + t;
  if (t < BKT && node < N) colcnt[node] = lh[t];
}

// --- per-bucket LDS histogram of row-id bytes -> rowcnt ---
__global__ void bhistr_k(const uint8_t* __restrict__ rowbuf, const int* __restrict__ bcur,
                         int cap, int* __restrict__ rowcnt, int N){
  __shared__ int lh[BKT];
  int b = blockIdx.x, t = threadIdx.x;
  if (t < BKT) lh[t] = 0;
  __syncthreads();
  int cnt = bcur[b]; if (cnt > cap) cnt = cap;
  const uint8_t* buf = rowbuf + (size_t)b * cap;
  for (int i = t; i < cnt; i += 256) atomicAdd(&lh[buf[i]], 1);
  __syncthreads();
  int node = b * BKT + t;
  if (t < BKT && node < N) rowcnt[node] = lh[t];
}

// --- scan pass 1 (block sums of colcnt) + fused dinv = (rowcnt+2)^-1/2 ---
__global__ void scan1_k(const int* __restrict__ cnt, const int* __restrict__ rowcnt,
                        float* __restrict__ dinv, int* __restrict__ bsum, int N){
  __shared__ int sh[256];
  int t = threadIdx.x;
  int base = blockIdx.x * CHUNK + t * 4;
  int s = 0;
  #pragma unroll
  for (int j = 0; j < 4; j++){
    int g = base + j;
    if (g < N){
      s += cnt[g];
      dinv[g] = 1.0f / sqrtf((float)rowcnt[g] + 2.0f);
    }
  }
  sh[t] = s; __syncthreads();
  for (int off = 128; off > 0; off >>= 1){
    if (t < off) sh[t] += sh[t + off];
    __syncthreads();
  }
  if (t == 0) bsum[blockIdx.x] = sh[0];
}

__global__ void scan2_k(const int* __restrict__ bsum, int* __restrict__ bpre, int NB){
  __shared__ int sh[128];
  int t = threadIdx.x;
  int v = (t < NB) ? bsum[t] : 0;
  sh[t] = v; __syncthreads();
  for (int off = 1; off < 128; off <<= 1){
    int x = (t >= off) ? sh[t - off] : 0;
    __syncthreads();
    sh[t] += x;
    __syncthreads();
  }
  if (t < NB) bpre[t] = sh[t] - v;
}

__global__ void scan3_k(const int* __restrict__ cnt, const int* __restrict__ bpre,
                        int* __restrict__ offsets, int N){
  __shared__ int sh[256];
  int t = threadIdx.x, b = blockIdx.x;
  int base = b * CHUNK + t * 4;
  int v[4]; int s = 0;
  #pragma unroll
  for (int j = 0; j < 4; j++){ int g = base + j; v[j] = (g < N) ? cnt[g] : 0; s += v[j]; }
  sh[t] = s; __syncthreads();
  for (int off = 1; off < 256; off <<= 1){
    int x = (t >= off) ? sh[t - off] : 0;
    __syncthreads();
    sh[t] += x;
    __syncthreads();
  }
  int run = sh[t] - s + bpre[b];
  #pragma unroll
  for (int j = 0; j < 4; j++){
    int g = base + j;
    if (g <= N) offsets[g] = run;
    run += v[j];
  }
}

// --- per-bucket CSR scatter: loff (offsets) doubles as running cursor ---
__global__ void bscat_k(const unsigned int* __restrict__ colbuf, const int* __restrict__ bcur,
                        int cap, const int* __restrict__ offsets,
                        int* __restrict__ csr_src, int N){
  __shared__ int loff[BKT];
  int b = blockIdx.x, t = threadIdx.x;
  int node = b * BKT + t;
  if (t < BKT) loff[t] = (node < N) ? offsets[node] : 0;
  __syncthreads();
  int cnt = bcur[b]; if (cnt > cap) cnt = cap;
  const unsigned int* buf = colbuf + (size_t)b * cap;
  for (int i = t; i < cnt; i += 256){
    unsigned int v = buf[i];
    int p = atomicAdd(&loff[v & 63], 1);
    csr_src[p] = (int)(v >> 6);
  }
}

// --- pack layer-0 gather matrix: XH[node][j] = (half(x), half(h)) ---
__global__ void pack0_k(const float* __restrict__ X, const float* __restrict__ H,
                        __half2* __restrict__ XH, int total){
  int i = blockIdx.x * 256 + threadIdx.x;
  if (i < total){
    __half2 v;
    v.x = __float2half_rn(X[i]);
    v.y = __float2half_rn(H[i]);
    XH[i] = v;
  }
}

// --- pack weights into MFMA B-fragment order + fused biases (see R8) ---
__global__ void packb_k(const float* __restrict__ Wxz, const float* __restrict__ Whz,
                        const float* __restrict__ Wxr, const float* __restrict__ Whr,
                        const float* __restrict__ Wxh, const float* __restrict__ Whh,
                        const float* __restrict__ bxz, const float* __restrict__ bhz,
                        const float* __restrict__ bxr, const float* __restrict__ bhr,
                        const float* __restrict__ bxh, const float* __restrict__ bhh,
                        _Float16* __restrict__ Bg, _Float16* __restrict__ Bo,
                        float* __restrict__ biasg, int L){
  const int PER = 24576 + 4096 + 192;
  int tid = blockIdx.x * 256 + threadIdx.x;
  if (tid >= L * PER) return;
  int l = tid / PER, r = tid % PER;
  if (r < 24576){
    int q = r;
    int s = q & 7, lane = (q >> 3) & 63, ks = (q >> 9) & 3, jt = q >> 11;
    int k = ks * 32 + (lane >> 4) * 8 + s;
    int b = jt >> 2;
    int j = (jt & 3) * 16 + (lane & 15);
    const float* Wx = (b == 0) ? Wxz : (b == 1) ? Wxr : Wxh;
    const float* Wh = (b == 0) ? Whz : Whr;
    float v;
    if (k < 64) v = Wx[(size_t)l * 4096 + k * 64 + j];
    else        v = (b == 2) ? 0.0f : Wh[(size_t)l * 4096 + (k - 64) * 64 + j];
    Bg[(size_t)l * 24576 + q] = (_Float16)v;
  } else if (r < 24576 + 4096){
    int q = r - 24576;
    int s = q & 7, lane = (q >> 3) & 63, ks = (q >> 9) & 1, jt = q >> 10;
    int k = ks * 32 + (lane >> 4) * 8 + s;
    int j = jt * 16 + (lane & 15);
    Bo[(size_t)l * 4096 + q] = (_Float16)Whh[(size_t)l * 4096 + k * 64 + j];
  } else {
    int j = r - (24576 + 4096);
    int b = j >> 6, jj = j & 63;
    float v = (b == 0) ? bxz[l * 64 + jj] + bhz[l * 64 + jj]
            : (b == 1) ? bxr[l * 64 + jj] + bhr[l * 64 + jj]
                       : bxh[l * 64 + jj] + bhh[l * 64 + jj];
    biasg[l * 192 + j] = v;
  }
}

// --- fused aggregation of (x,h) fp16 pairs, unroll 4; writes AXAH fp16 [node][128] ---
__global__ void agg2_k(const __half2* __restrict__ XH,
                       const int* __restrict__ offsets, const int* __restrict__ src,
                       const float* __restrict__ dinv,
                       _Float16* __restrict__ AXAH, int N){
  int wid = (blockIdx.x * blockDim.x + threadIdx.x) >> 6;
  int lane = threadIdx.x & 63;
  if (wid >= N) return;
  float dv = dinv[wid];
  float selfw = 2.0f * dv * dv;
  size_t me = (size_t)wid * DD + lane;
  float2 sf = __half22float2(XH[me]);
  float ax1 = selfw * sf.x, ah1 = selfw * sf.y;
  float ax2 = 0.0f, ah2 = 0.0f;
  float ax3 = 0.0f, ah3 = 0.0f;
  float ax4 = 0.0f, ah4 = 0.0f;
  int s0 = offsets[wid], s1 = offsets[wid + 1];
  int e = s0;
  for (; e + 4 <= s1; e += 4){
    int sa = src[e], sb = src[e + 1], sc = src[e + 2], sd = src[e + 3];
    float wa = dinv[sa] * dv, wb = dinv[sb] * dv;
    float wc = dinv[sc] * dv, wd = dinv[sd] * dv;
    float2 fa = __half22float2(XH[(size_t)sa * DD + lane]);
    float2 fb = __half22float2(XH[(size_t)sb * DD + lane]);
    float2 fc = __half22float2(XH[(size_t)sc * DD + lane]);
    float2 fd = __half22float2(XH[(size_t)sd * DD + lane]);
    ax1 += wa * fa.x;  ah1 += wa * fa.y;
    ax2 += wb * fb.x;  ah2 += wb * fb.y;
    ax3 += wc * fc.x;  ah3 += wc * fc.y;
    ax4 += wd * fd.x;  ah4 += wd * fd.y;
  }
  for (; e < s1; ++e){
    int sa = src[e];
    float wa = dinv[sa] * dv;
    float2 fa = __half22float2(XH[(size_t)sa * DD + lane]);
    ax1 += wa * fa.x;
    ah1 += wa * fa.y;
  }
  size_t o = (size_t)wid * 128 + lane;
  AXAH[o]      = (_Float16)((ax1 + ax2) + (ax3 + ax4));
  AXAH[o + 64] = (_Float16)((ah1 + ah2) + (ah3 + ah4));
}

// --- aggregation of fp16 rows (r*h), unroll 4; writes Arh fp16 [node][64] ---
__global__ void agg1_k(const _Float16* __restrict__ RH,
                       const int* __restrict__ offsets, const int* __restrict__ src,
                       const float* __restrict__ dinv,
                       _Float16* __restrict__ Arh, int N){
  int wid = (blockIdx.x * blockDim.x + threadIdx.x) >> 6;
  int lane = threadIdx.x & 63;
  if (wid >= N) return;
  float dv = dinv[wid];
  float selfw = 2.0f * dv * dv;
  size_t me = (size_t)wid * DD + lane;
  float ax1 = selfw * (float)RH[me];
  float ax2 = 0.0f, ax3 = 0.0f, ax4 = 0.0f;
  int s0 = offsets[wid], s1 = offsets[wid + 1];
  int e = s0;
  for (; e + 4 <= s1; e += 4){
    int sa = src[e], sb = src[e + 1], sc = src[e + 2], sd = src[e + 3];
    float wa = dinv[sa] * dv, wb = dinv[sb] * dv;
    float wc = dinv[sc] * dv, wd = dinv[sd] * dv;
    ax1 += wa * (float)RH[(size_t)sa * DD + lane];
    ax2 += wb * (float)RH[(size_t)sb * DD + lane];
    ax3 += wc * (float)RH[(size_t)sc * DD + lane];
    ax4 += wd * (float)RH[(size_t)sd * DD + lane];
  }
  for (; e < s1; ++e){
    ax1 += (dinv[src[e]] * dv) * (float)RH[(size_t)src[e] * DD + lane];
  }
  Arh[me] = (_Float16)((ax1 + ax2) + (ax3 + ax4));
}

// --- MFMA gate kernel (see R8): C(N x 192) = AXAH @ Bg + bias ---
__global__ __launch_bounds__(256) void gatem_k(
    const _Float16* __restrict__ AXAH, const float* __restrict__ Hh,
    const _Float16* __restrict__ Bg, const float* __restrict__ biasg,
    _Float16* __restrict__ zb, _Float16* __restrict__ rhb,
    _Float16* __restrict__ t1b, int N)
{
  const int lane = threadIdx.x & 63;
  const int wv   = threadIdx.x >> 6;
  const long nbase = ((long)blockIdx.x * 4 + wv) * 32;
  if (nbase >= N) return;
  const int m  = lane & 15;
  const int kb = lane >> 4;

  f32x4 acc[2][12];
  #pragma unroll
  for (int jt = 0; jt < 12; jt++){
    float bv = biasg[jt * 16 + m];
    f32x4 b4 = {bv, bv, bv, bv};
    acc[0][jt] = b4;
    acc[1][jt] = b4;
  }

  #pragma unroll 1
  for (int ks = 0; ks < 4; ks++){
    f16x8 af0, af1;
    {
      long r0 = nbase + m;           if (r0 >= N) r0 = N - 1;
      long r1 = nbase + 16 + m;      if (r1 >= N) r1 = N - 1;
      af0 = *(const f16x8*)(AXAH + (size_t)r0 * 128 + ks * 32 + kb * 8);
      af1 = *(const f16x8*)(AXAH + (size_t)r1 * 128 + ks * 32 + kb * 8);
    }
    #pragma unroll
    for (int jt = 0; jt < 12; jt++){
      f16x8 bf = *(const f16x8*)(Bg + ((size_t)(jt * 4 + ks) * 64 + lane) * 8);
      acc[0][jt] = __builtin_amdgcn_mfma_f32_16x16x32_f16(af0, bf, acc[0][jt], 0, 0, 0);
      acc[1][jt] = __builtin_amdgcn_mfma_f32_16x16x32_f16(af1, bf, acc[1][jt], 0, 0, 0);
    }
  }

  #pragma unroll
  for (int mt = 0; mt < 2; mt++){
    #pragma unroll
    for (int i = 0; i < 4; i++){
      long row = nbase + mt * 16 + kb * 4 + i;
      if (row < N){
        #pragma unroll
        for (int jq = 0; jq < 4; jq++){
          int j = jq * 16 + m;
          size_t o = (size_t)row * 64 + j;
          float zpre = acc[mt][jq][i];
          float rpre = acc[mt][4 + jq][i];
          float t1v  = acc[mt][8 + jq][i];
          float hv = Hh[o];
          zb[o]  = (_Float16)(1.0f / (1.0f + __expf(-zpre)));
          rhb[o] = (_Float16)(hv / (1.0f + __expf(-rpre)));
          t1b[o] = (_Float16)t1v;
        }
      }
    }
  }
}

// --- MFMA output kernel (see R8): acc = t1 + Arh @ Bo; GRU combine ---
__global__ __launch_bounds__(256) void outm_k(
    const _Float16* __restrict__ Arh, const _Float16* __restrict__ t1b,
    const _Float16* __restrict__ zb, const float* __restrict__ Hh,
    const _Float16* __restrict__ Bo,
    float* __restrict__ o1, float* __restrict__ o2,
    const float* __restrict__ hNext, __half2* __restrict__ XHnext,
    int doPack, int N)
{
  const int lane = threadIdx.x & 63;
  const int wv   = threadIdx.x >> 6;
  const long nbase = ((long)blockIdx.x * 4 + wv) * 32;
  if (nbase >= N) return;
  const int m  = lane & 15;
  const int kb = lane >> 4;

  f32x4 acc[2][4];
  #pragma unroll
  for (int mt = 0; mt < 2; mt++){
    #pragma unroll
    for (int jt = 0; jt < 4; jt++){
      #pragma unroll
      for (int i = 0; i < 4; i++){
        long row = nbase + mt * 16 + kb * 4 + i;
        if (row >= N) row = N - 1;
        acc[mt][jt][i] = (float)t1b[(size_t)row * 64 + jt * 16 + m];
      }
    }
  }

  #pragma unroll
  for (int ks = 0; ks < 2; ks++){
    f16x8 af0, af1;
    {
      long r0 = nbase + m;           if (r0 >= N) r0 = N - 1;
      long r1 = nbase + 16 + m;      if (r1 >= N) r1 = N - 1;
      af0 = *(const f16x8*)(Arh + (size_t)r0 * 64 + ks * 32 + kb * 8);
      af1 = *(const f16x8*)(Arh + (size_t)r1 * 64 + ks * 32 + kb * 8);
    }
    #pragma unroll
    for (int jt = 0; jt < 4; jt++){
      f16x8 bf = *(const f16x8*)(Bo + ((size_t)(jt * 2 + ks) * 64 + lane) * 8);
      acc[0][jt] = __builtin_amdgcn_mfma_f32_16x16x32_f16(af0, bf, acc[0][jt], 0, 0, 0);
      acc[1][jt] = __builtin_amdgcn_mfma_f32_16x16x32_f16(af1, bf, acc[1][jt], 0, 0, 0);
    }
  }

  #pragma unroll
  for (int mt = 0; mt < 2; mt++){
    #pragma unroll
    for (int i = 0; i < 4; i++){
      long row = nbase + mt * 16 + kb * 4 + i;
      if (row < N){
        #pragma unroll
        for (int jt = 0; jt < 4; jt++){
          int j = jt * 16 + m;
          size_t o = (size_t)row * 64 + j;
          float e = __expf(2.0f * acc[mt][jt][i]);
          float ht = 1.0f - 2.0f / (e + 1.0f);
          float z = (float)zb[o];
          float hv = Hh[o];
          float ho = z * hv + (1.0f - z) * ht;
          o1[o] = ho;
          o2[o] = ho;
          if (doPack){
            __half2 v;
            v.x = __float2half_rn(ho);
            v.y = __float2half_rn(hNext[o]);
            XHnext[o] = v;
          }
        }
      }
    }
  }
}

extern "C" void kernel_launch(void* const* d_in, const int* in_sizes, int n_in,
                              void* d_out, int out_size, void* d_ws, size_t ws_size,
                              hipStream_t stream){
  const float* inp = (const float*)d_in[0];
  const float* h   = (const float*)d_in[1];
  const int*   edg = (const int*)d_in[2];
  const float* Wxz = (const float*)d_in[3];
  const float* Whz = (const float*)d_in[4];
  const float* Wxr = (const float*)d_in[5];
  const float* Whr = (const float*)d_in[6];
  const float* Wxh = (const float*)d_in[7];
  const float* Whh = (const float*)d_in[8];
  const float* bxz = (const float*)d_in[9];
  const float* bhz = (const float*)d_in[10];
  const float* bxr = (const float*)d_in[11];
  const float* bhr = (const float*)d_in[12];
  const float* bxh = (const float*)d_in[13];
  const float* bhh = (const float*)d_in[14];
  float* out = (float*)d_out;

  const int ND = in_sizes[0];
  const int N  = ND / DD;
  const int E  = in_sizes[2] / 2;
  const int L  = in_sizes[1] / ND;

  const int nbkt = divup(N, BKT);
  const int cap  = E / nbkt + E / (2 * nbkt) + 64;   // ~1.5x mean + slack

  char* p = (char*)d_ws;
  auto alloc = [&](size_t bytes) -> void* {
    void* r = (void*)p;
    p += ((bytes + 255) / 256) * 256;
    return r;
  };
  auto a256 = [](size_t b) -> size_t { return ((b + 255) / 256) * 256; };

  int*      bcur    = (int*)alloc((size_t)2 * nbkt * 4);   // bcur_c | bcur_r
  int*      bcur_c  = bcur;
  int*      bcur_r  = bcur + nbkt;
  int*      offsets = (int*)alloc((size_t)(N + 1) * 4);
  int*      bsum    = (int*)alloc(128 * 4);
  int*      bpre    = (int*)alloc(128 * 4);
  float*    dinv    = (float*)alloc((size_t)N * 4);
  int*      colcnt  = (int*)alloc((size_t)2 * N * 4);      // colcnt | rowcnt
  int*      rowcnt  = colcnt + N;
  int*      csr_src = (int*)alloc((size_t)E * 4);
  __half2*  XH      = (__half2*)alloc((size_t)ND * 4);     // (x,h) fp16 pairs
  _Float16* Bg      = (_Float16*)alloc((size_t)L * 24576 * 2);
  _Float16* Bo      = (_Float16*)alloc((size_t)L * 4096 * 2);
  float*    biasg   = (float*)alloc((size_t)L * 192 * 4);

  // overlay: {colbuf|rowbuf} (CSR build) reuses {AXAH|Arh|zb|t1b|rhb} (layer loop)
  size_t colbuf_b = a256((size_t)nbkt * cap * 4);
  size_t rowbuf_b = a256((size_t)nbkt * cap);
  size_t axah_b   = a256((size_t)N * 128 * 2);
  size_t nd2_b    = a256((size_t)ND * 2);
  size_t ov_b     = axah_b + 4 * nd2_b;
  if (colbuf_b + rowbuf_b > ov_b) ov_b = colbuf_b + rowbuf_b;
  char* ov = (char*)alloc(ov_b);
  unsigned int* colbuf = (unsigned int*)ov;
  uint8_t*      rowbuf = (uint8_t*)(ov + colbuf_b);
  _Float16* AXAH = (_Float16*)ov;
  _Float16* Arh  = (_Float16*)(ov + axah_b);
  _Float16* zb   = (_Float16*)(ov + axah_b + nd2_b);
  _Float16* t1b  = (_Float16*)(ov + axah_b + 2 * nd2_b);
  _Float16* rhb  = (_Float16*)(ov + axah_b + 3 * nd2_b);

  hipMemsetAsync(bcur, 0, (size_t)2 * nbkt * 4, stream);

  // --- CSR build (bucketed; replaces full-footprint atomic histogram) ---
  if ((E & 3) == 0){
    const int E4 = E / 4;
    bucket1v_k<<<divup(E4, 256), 256, 0, stream>>>(edg, bcur_c, bcur_r, colbuf, rowbuf, cap, E4);
  } else {
    bucket1s_k<<<divup(E, 256), 256, 0, stream>>>(edg, bcur_c, bcur_r, colbuf, rowbuf, cap, E);
  }
  bhistr_k<<<nbkt, 256, 0, stream>>>(rowbuf, bcur_r, cap, rowcnt, N);
  bhistc_k<<<nbkt, 256, 0, stream>>>(colbuf, bcur_c, cap, colcnt, N);
  const int NB = divup(N, CHUNK);
  scan1_k<<<NB, 256, 0, stream>>>(colcnt, rowcnt, dinv, bsum, N);
  scan2_k<<<1, 128, 0, stream>>>(bsum, bpre, NB);
  scan3_k<<<NB, 256, 0, stream>>>(colcnt, bpre, offsets, N);
  bscat_k<<<nbkt, 256, 0, stream>>>(colbuf, bcur_c, cap, offsets, csr_src, N);

  pack0_k<<<divup(ND, 256), 256, 0, stream>>>(inp, h, XH, ND);
  {
    const int PER = 24576 + 4096 + 192;
    packb_k<<<divup(L * PER, 256), 256, 0, stream>>>(
        Wxz, Whz, Wxr, Whr, Wxh, Whh,
        bxz, bhz, bxr, bhr, bxh, bhh, Bg, Bo, biasg, L);
  }

  const int aggBlocks = divup(N, 4);     // 4 waves (nodes) per 256-thread block
  const int mBlocks   = divup(N, 128);   // 4 waves x 32 nodes per block

  for (int l = 0; l < L; l++){
    const float* Hh = h + (size_t)l * ND;
    agg2_k<<<aggBlocks, 256, 0, stream>>>(XH, offsets, csr_src, dinv, AXAH, N);
    gatem_k<<<mBlocks, 256, 0, stream>>>(AXAH, Hh,
        Bg + (size_t)l * 24576, biasg + (size_t)l * 192, zb, rhb, t1b, N);
    agg1_k<<<aggBlocks, 256, 0, stream>>>(rhb, offsets, csr_src, dinv, Arh, N);
    const int doPack = (l + 1 < L);
    outm_k<<<mBlocks, 256, 0, stream>>>(Arh, t1b, zb, Hh,
        Bo + (size_t)l * 4096,
        out + (size_t)l * ND, out + (size_t)L * ND + (size_t)l * ND,
        h + (size_t)(l + 1 < L ? l + 1 : l) * ND, XH, doPack, N);
  }
}

// Round 10
// 525.803 us; speedup vs baseline: 1.4502x; 1.4502x over previous
//
#include <hip/hip_runtime.h>
#include <hip/hip_fp16.h>
#include <math.h>
#include <stdint.h>

#define DD 64
#define CHUNK 1024
#define NRG 512        // nodes per range (9 bits)
#define BB  128        // binning blocks

using f16x8 = __attribute__((ext_vector_type(8))) _Float16;
using f32x4 = __attribute__((ext_vector_type(4))) float;

static inline int divup(int a, int b){ return (a + b - 1) / b; }

// ---------------------------------------------------------------------------
// CSR build with ZERO global atomics (R9 lesson: memory-side RMW ~150ns/op on
// hot words, 32B dirty sector per atomic regardless of footprint).
// bin_k: block b bins its edge slice into per-(b,range) sub-buffers using LDS
// cursors; payload row<<9|collow (col buffers) and rowlow (row buffers).
// ---------------------------------------------------------------------------
__global__ __launch_bounds__(256) void bin_k(
    const int* __restrict__ edg, int E, int per, int nr, int cap,
    unsigned int* __restrict__ bufc, unsigned short* __restrict__ bufr,
    int* __restrict__ cntc, int* __restrict__ cntr)
{
  extern __shared__ int cur[];            // [nr] col cursors | [nr] row cursors
  int* curc = cur;
  int* curr = cur + nr;
  const int b = blockIdx.x, t = threadIdx.x;
  for (int i = t; i < 2 * nr; i += 256) cur[i] = 0;
  __syncthreads();
  const int e0 = b * per;
  const int e1 = (e0 + per < E) ? e0 + per : E;
  unsigned int* mybufc = bufc + (size_t)b * nr * cap;
  unsigned short* mybufr = bufr + (size_t)b * nr * cap;
  for (int e = e0 + t; e < e1; e += 256){
    int r = edg[e];
    int c = edg[E + e];
    int rg = c >> 9;
    int p = atomicAdd(&curc[rg], 1);      // LDS atomic
    if (p < cap) mybufc[rg * cap + p] = ((unsigned int)r << 9) | (unsigned int)(c & 511);
    int rr = r >> 9;
    int q = atomicAdd(&curr[rr], 1);      // LDS atomic
    if (q < cap) mybufr[rr * cap + q] = (unsigned short)(r & 511);
  }
  __syncthreads();
  for (int i = t; i < nr; i += 256){
    int vc = curc[i]; cntc[b * nr + i] = vc < cap ? vc : cap;
    int vr = curr[i]; cntr[b * nr + i] = vr < cap ? vr : cap;
  }
}

// --- per-range LDS histograms over all sub-buffers -> colcnt, rowcnt ---
__global__ __launch_bounds__(256) void cnt2_k(
    const unsigned int* __restrict__ bufc, const unsigned short* __restrict__ bufr,
    const int* __restrict__ cntc, const int* __restrict__ cntr,
    int nb, int nr, int cap,
    int* __restrict__ colcnt, int* __restrict__ rowcnt, int N)
{
  __shared__ int lhc[NRG];
  __shared__ int lhr[NRG];
  __shared__ int lcc[BB];
  __shared__ int lcr[BB];
  const int rg = blockIdx.x, t = threadIdx.x;
  for (int i = t; i < NRG; i += 256){ lhc[i] = 0; lhr[i] = 0; }
  for (int i = t; i < nb; i += 256){ lcc[i] = cntc[i * nr + rg]; lcr[i] = cntr[i * nr + rg]; }
  __syncthreads();
  const int wv = t >> 6, lane = t & 63;
  for (int b = wv; b < nb; b += 4){
    const unsigned int* buf = bufc + ((size_t)b * nr + rg) * cap;
    int cnt = lcc[b];
    for (int i = lane; i < cnt; i += 64) atomicAdd(&lhc[buf[i] & 511], 1);
    const unsigned short* bufR = bufr + ((size_t)b * nr + rg) * cap;
    int cntR = lcr[b];
    for (int i = lane; i < cntR; i += 64) atomicAdd(&lhr[bufR[i]], 1);
  }
  __syncthreads();
  for (int i = t; i < NRG; i += 256){
    int node = rg * NRG + i;
    if (node < N){ colcnt[node] = lhc[i]; rowcnt[node] = lhr[i]; }
  }
}

// --- scan pass 1 (block sums of colcnt) + fused dinv = (rowcnt+2)^-1/2 ---
__global__ void scan1_k(const int* __restrict__ cnt, const int* __restrict__ rowcnt,
                        float* __restrict__ dinv, int* __restrict__ bsum, int N){
  __shared__ int sh[256];
  int t = threadIdx.x;
  int base = blockIdx.x * CHUNK + t * 4;
  int s = 0;
  #pragma unroll
  for (int j = 0; j < 4; j++){
    int g = base + j;
    if (g < N){
      s += cnt[g];
      dinv[g] = 1.0f / sqrtf((float)rowcnt[g] + 2.0f);
    }
  }
  sh[t] = s; __syncthreads();
  for (int off = 128; off > 0; off >>= 1){
    if (t < off) sh[t] += sh[t + off];
    __syncthreads();
  }
  if (t == 0) bsum[blockIdx.x] = sh[0];
}

__global__ void scan2_k(const int* __restrict__ bsum, int* __restrict__ bpre, int NB){
  __shared__ int sh[128];
  int t = threadIdx.x;
  int v = (t < NB) ? bsum[t] : 0;
  sh[t] = v; __syncthreads();
  for (int off = 1; off < 128; off <<= 1){
    int x = (t >= off) ? sh[t - off] : 0;
    __syncthreads();
    sh[t] += x;
    __syncthreads();
  }
  if (t < NB) bpre[t] = sh[t] - v;
}

__global__ void scan3_k(const int* __restrict__ cnt, const int* __restrict__ bpre,
                        int* __restrict__ offsets, int N){
  __shared__ int sh[256];
  int t = threadIdx.x, b = blockIdx.x;
  int base = b * CHUNK + t * 4;
  int v[4]; int s = 0;
  #pragma unroll
  for (int j = 0; j < 4; j++){ int g = base + j; v[j] = (g < N) ? cnt[g] : 0; s += v[j]; }
  sh[t] = s; __syncthreads();
  for (int off = 1; off < 256; off <<= 1){
    int x = (t >= off) ? sh[t - off] : 0;
    __syncthreads();
    sh[t] += x;
    __syncthreads();
  }
  int run = sh[t] - s + bpre[b];
  #pragma unroll
  for (int j = 0; j < 4; j++){
    int g = base + j;
    if (g <= N) offsets[g] = run;
    run += v[j];
  }
}

// --- per-range CSR scatter: LDS cursors init from offsets; zero global atomics ---
__global__ __launch_bounds__(256) void scat_k(
    const unsigned int* __restrict__ bufc, const int* __restrict__ cntc,
    int nb, int nr, int cap, const int* __restrict__ offsets,
    int* __restrict__ csr_src, int N)
{
  __shared__ int loff[NRG];
  __shared__ int lcc[BB];
  const int rg = blockIdx.x, t = threadIdx.x;
  for (int i = t; i < NRG; i += 256){
    int node = rg * NRG + i;
    loff[i] = (node < N) ? offsets[node] : 0;
  }
  for (int i = t; i < nb; i += 256) lcc[i] = cntc[i * nr + rg];
  __syncthreads();
  const int wv = t >> 6, lane = t & 63;
  for (int b = wv; b < nb; b += 4){
    const unsigned int* buf = bufc + ((size_t)b * nr + rg) * cap;
    int cnt = lcc[b];
    for (int i = lane; i < cnt; i += 64){
      unsigned int v = buf[i];
      int p = atomicAdd(&loff[v & 511], 1);   // LDS atomic
      csr_src[p] = (int)(v >> 9);
    }
  }
}

// --- pack layer-0 gather matrix: XH[node][j] = (half(x), half(h)) ---
__global__ void pack0_k(const float* __restrict__ X, const float* __restrict__ H,
                        __half2* __restrict__ XH, int total){
  int i = blockIdx.x * 256 + threadIdx.x;
  if (i < total){
    __half2 v;
    v.x = __float2half_rn(X[i]);
    v.y = __float2half_rn(H[i]);
    XH[i] = v;
  }
}

// --- pack weights into MFMA B-fragment order + fused biases (see R8) ---
__global__ void packb_k(const float* __restrict__ Wxz, const float* __restrict__ Whz,
                        const float* __restrict__ Wxr, const float* __restrict__ Whr,
                        const float* __restrict__ Wxh, const float* __restrict__ Whh,
                        const float* __restrict__ bxz, const float* __restrict__ bhz,
                        const float* __restrict__ bxr, const float* __restrict__ bhr,
                        const float* __restrict__ bxh, const float* __restrict__ bhh,
                        _Float16* __restrict__ Bg, _Float16* __restrict__ Bo,
                        float* __restrict__ biasg, int L){
  const int PER = 24576 + 4096 + 192;
  int tid = blockIdx.x * 256 + threadIdx.x;
  if (tid >= L * PER) return;
  int l = tid / PER, r = tid % PER;
  if (r < 24576){
    int q = r;
    int s = q & 7, lane = (q >> 3) & 63, ks = (q >> 9) & 3, jt = q >> 11;
    int k = ks * 32 + (lane >> 4) * 8 + s;
    int b = jt >> 2;
    int j = (jt & 3) * 16 + (lane & 15);
    const float* Wx = (b == 0) ? Wxz : (b == 1) ? Wxr : Wxh;
    const float* Wh = (b == 0) ? Whz : Whr;
    float v;
    if (k < 64) v = Wx[(size_t)l * 4096 + k * 64 + j];
    else        v = (b == 2) ? 0.0f : Wh[(size_t)l * 4096 + (k - 64) * 64 + j];
    Bg[(size_t)l * 24576 + q] = (_Float16)v;
  } else if (r < 24576 + 4096){
    int q = r - 24576;
    int s = q & 7, lane = (q >> 3) & 63, ks = (q >> 9) & 1, jt = q >> 10;
    int k = ks * 32 + (lane >> 4) * 8 + s;
    int j = jt * 16 + (lane & 15);
    Bo[(size_t)l * 4096 + q] = (_Float16)Whh[(size_t)l * 4096 + k * 64 + j];
  } else {
    int j = r - (24576 + 4096);
    int b = j >> 6, jj = j & 63;
    float v = (b == 0) ? bxz[l * 64 + jj] + bhz[l * 64 + jj]
            : (b == 1) ? bxr[l * 64 + jj] + bhr[l * 64 + jj]
                       : bxh[l * 64 + jj] + bhh[l * 64 + jj];
    biasg[l * 192 + j] = v;
  }
}

// --- fused aggregation of (x,h) fp16 pairs, unroll 4; writes AXAH fp16 [node][128] ---
__global__ void agg2_k(const __half2* __restrict__ XH,
                       const int* __restrict__ offsets, const int* __restrict__ src,
                       const float* __restrict__ dinv,
                       _Float16* __restrict__ AXAH, int N){
  int wid = (blockIdx.x * blockDim.x + threadIdx.x) >> 6;
  int lane = threadIdx.x & 63;
  if (wid >= N) return;
  float dv = dinv[wid];
  float selfw = 2.0f * dv * dv;
  size_t me = (size_t)wid * DD + lane;
  float2 sf = __half22float2(XH[me]);
  float ax1 = selfw * sf.x, ah1 = selfw * sf.y;
  float ax2 = 0.0f, ah2 = 0.0f;
  float ax3 = 0.0f, ah3 = 0.0f;
  float ax4 = 0.0f, ah4 = 0.0f;
  int s0 = offsets[wid], s1 = offsets[wid + 1];
  int e = s0;
  for (; e + 4 <= s1; e += 4){
    int sa = src[e], sb = src[e + 1], sc = src[e + 2], sd = src[e + 3];
    float wa = dinv[sa] * dv, wb = dinv[sb] * dv;
    float wc = dinv[sc] * dv, wd = dinv[sd] * dv;
    float2 fa = __half22float2(XH[(size_t)sa * DD + lane]);
    float2 fb = __half22float2(XH[(size_t)sb * DD + lane]);
    float2 fc = __half22float2(XH[(size_t)sc * DD + lane]);
    float2 fd = __half22float2(XH[(size_t)sd * DD + lane]);
    ax1 += wa * fa.x;  ah1 += wa * fa.y;
    ax2 += wb * fb.x;  ah2 += wb * fb.y;
    ax3 += wc * fc.x;  ah3 += wc * fc.y;
    ax4 += wd * fd.x;  ah4 += wd * fd.y;
  }
  for (; e < s1; ++e){
    int sa = src[e];
    float wa = dinv[sa] * dv;
    float2 fa = __half22float2(XH[(size_t)sa * DD + lane]);
    ax1 += wa * fa.x;
    ah1 += wa * fa.y;
  }
  size_t o = (size_t)wid * 128 + lane;
  AXAH[o]      = (_Float16)((ax1 + ax2) + (ax3 + ax4));
  AXAH[o + 64] = (_Float16)((ah1 + ah2) + (ah3 + ah4));
}

// --- aggregation of fp16 rows (r*h), unroll 4; writes Arh fp16 [node][64] ---
__global__ void agg1_k(const _Float16* __restrict__ RH,
                       const int* __restrict__ offsets, const int* __restrict__ src,
                       const float* __restrict__ dinv,
                       _Float16* __restrict__ Arh, int N){
  int wid = (blockIdx.x * blockDim.x + threadIdx.x) >> 6;
  int lane = threadIdx.x & 63;
  if (wid >= N) return;
  float dv = dinv[wid];
  float selfw = 2.0f * dv * dv;
  size_t me = (size_t)wid * DD + lane;
  float ax1 = selfw * (float)RH[me];
  float ax2 = 0.0f, ax3 = 0.0f, ax4 = 0.0f;
  int s0 = offsets[wid], s1 = offsets[wid + 1];
  int e = s0;
  for (; e + 4 <= s1; e += 4){
    int sa = src[e], sb = src[e + 1], sc = src[e + 2], sd = src[e + 3];
    float wa = dinv[sa] * dv, wb = dinv[sb] * dv;
    float wc = dinv[sc] * dv, wd = dinv[sd] * dv;
    ax1 += wa * (float)RH[(size_t)sa * DD + lane];
    ax2 += wb * (float)RH[(size_t)sb * DD + lane];
    ax3 += wc * (float)RH[(size_t)sc * DD + lane];
    ax4 += wd * (float)RH[(size_t)sd * DD + lane];
  }
  for (; e < s1; ++e){
    ax1 += (dinv[src[e]] * dv) * (float)RH[(size_t)src[e] * DD + lane];
  }
  Arh[me] = (_Float16)((ax1 + ax2) + (ax3 + ax4));
}

// --- MFMA gate kernel (see R8): C(N x 192) = AXAH @ Bg + bias ---
__global__ __launch_bounds__(256) void gatem_k(
    const _Float16* __restrict__ AXAH, const float* __restrict__ Hh,
    const _Float16* __restrict__ Bg, const float* __restrict__ biasg,
    _Float16* __restrict__ zb, _Float16* __restrict__ rhb,
    _Float16* __restrict__ t1b, int N)
{
  const int lane = threadIdx.x & 63;
  const int wv   = threadIdx.x >> 6;
  const long nbase = ((long)blockIdx.x * 4 + wv) * 32;
  if (nbase >= N) return;
  const int m  = lane & 15;
  const int kb = lane >> 4;

  f32x4 acc[2][12];
  #pragma unroll
  for (int jt = 0; jt < 12; jt++){
    float bv = biasg[jt * 16 + m];
    f32x4 b4 = {bv, bv, bv, bv};
    acc[0][jt] = b4;
    acc[1][jt] = b4;
  }

  #pragma unroll 1
  for (int ks = 0; ks < 4; ks++){
    f16x8 af0, af1;
    {
      long r0 = nbase + m;           if (r0 >= N) r0 = N - 1;
      long r1 = nbase + 16 + m;      if (r1 >= N) r1 = N - 1;
      af0 = *(const f16x8*)(AXAH + (size_t)r0 * 128 + ks * 32 + kb * 8);
      af1 = *(const f16x8*)(AXAH + (size_t)r1 * 128 + ks * 32 + kb * 8);
    }
    #pragma unroll
    for (int jt = 0; jt < 12; jt++){
      f16x8 bf = *(const f16x8*)(Bg + ((size_t)(jt * 4 + ks) * 64 + lane) * 8);
      acc[0][jt] = __builtin_amdgcn_mfma_f32_16x16x32_f16(af0, bf, acc[0][jt], 0, 0, 0);
      acc[1][jt] = __builtin_amdgcn_mfma_f32_16x16x32_f16(af1, bf, acc[1][jt], 0, 0, 0);
    }
  }

  #pragma unroll
  for (int mt = 0; mt < 2; mt++){
    #pragma unroll
    for (int i = 0; i < 4; i++){
      long row = nbase + mt * 16 + kb * 4 + i;
      if (row < N){
        #pragma unroll
        for (int jq = 0; jq < 4; jq++){
          int j = jq * 16 + m;
          size_t o = (size_t)row * 64 + j;
          float zpre = acc[mt][jq][i];
          float rpre = acc[mt][4 + jq][i];
          float t1v  = acc[mt][8 + jq][i];
          float hv = Hh[o];
          zb[o]  = (_Float16)(1.0f / (1.0f + __expf(-zpre)));
          rhb[o] = (_Float16)(hv / (1.0f + __expf(-rpre)));
          t1b[o] = (_Float16)t1v;
        }
      }
    }
  }
}

// --- MFMA output kernel (see R8): acc = t1 + Arh @ Bo; GRU combine ---
__global__ __launch_bounds__(256) void outm_k(
    const _Float16* __restrict__ Arh, const _Float16* __restrict__ t1b,
    const _Float16* __restrict__ zb, const float* __restrict__ Hh,
    const _Float16* __restrict__ Bo,
    float* __restrict__ o1, float* __restrict__ o2,
    const float* __restrict__ hNext, __half2* __restrict__ XHnext,
    int doPack, int N)
{
  const int lane = threadIdx.x & 63;
  const int wv   = threadIdx.x >> 6;
  const long nbase = ((long)blockIdx.x * 4 + wv) * 32;
  if (nbase >= N) return;
  const int m  = lane & 15;
  const int kb = lane >> 4;

  f32x4 acc[2][4];
  #pragma unroll
  for (int mt = 0; mt < 2; mt++){
    #pragma unroll
    for (int jt = 0; jt < 4; jt++){
      #pragma unroll
      for (int i = 0; i < 4; i++){
        long row = nbase + mt * 16 + kb * 4 + i;
        if (row >= N) row = N - 1;
        acc[mt][jt][i] = (float)t1b[(size_t)row * 64 + jt * 16 + m];
      }
    }
  }

  #pragma unroll
  for (int ks = 0; ks < 2; ks++){
    f16x8 af0, af1;
    {
      long r0 = nbase + m;           if (r0 >= N) r0 = N - 1;
      long r1 = nbase + 16 + m;      if (r1 >= N) r1 = N - 1;
      af0 = *(const f16x8*)(Arh + (size_t)r0 * 64 + ks * 32 + kb * 8);
      af1 = *(const f16x8*)(Arh + (size_t)r1 * 64 + ks * 32 + kb * 8);
    }
    #pragma unroll
    for (int jt = 0; jt < 4; jt++){
      f16x8 bf = *(const f16x8*)(Bo + ((size_t)(jt * 2 + ks) * 64 + lane) * 8);
      acc[0][jt] = __builtin_amdgcn_mfma_f32_16x16x32_f16(af0, bf, acc[0][jt], 0, 0, 0);
      acc[1][jt] = __builtin_amdgcn_mfma_f32_16x16x32_f16(af1, bf, acc[1][jt], 0, 0, 0);
    }
  }

  #pragma unroll
  for (int mt = 0; mt < 2; mt++){
    #pragma unroll
    for (int i = 0; i < 4; i++){
      long row = nbase + mt * 16 + kb * 4 + i;
      if (row < N){
        #pragma unroll
        for (int jt = 0; jt < 4; jt++){
          int j = jt * 16 + m;
          size_t o = (size_t)row * 64 + j;
          float e = __expf(2.0f * acc[mt][jt][i]);
          float ht = 1.0f - 2.0f / (e + 1.0f);
          float z = (float)zb[o];
          float hv = Hh[o];
          float ho = z * hv + (1.0f - z) * ht;
          o1[o] = ho;
          o2[o] = ho;
          if (doPack){
            __half2 v;
            v.x = __float2half_rn(ho);
            v.y = __float2half_rn(hNext[o]);
            XHnext[o] = v;
          }
        }
      }
    }
  }
}

extern "C" void kernel_launch(void* const* d_in, const int* in_sizes, int n_in,
                              void* d_out, int out_size, void* d_ws, size_t ws_size,
                              hipStream_t stream){
  const float* inp = (const float*)d_in[0];
  const float* h   = (const float*)d_in[1];
  const int*   edg = (const int*)d_in[2];
  const float* Wxz = (const float*)d_in[3];
  const float* Whz = (const float*)d_in[4];
  const float* Wxr = (const float*)d_in[5];
  const float* Whr = (const float*)d_in[6];
  const float* Wxh = (const float*)d_in[7];
  const float* Whh = (const float*)d_in[8];
  const float* bxz = (const float*)d_in[9];
  const float* bhz = (const float*)d_in[10];
  const float* bxr = (const float*)d_in[11];
  const float* bhr = (const float*)d_in[12];
  const float* bxh = (const float*)d_in[13];
  const float* bhh = (const float*)d_in[14];
  float* out = (float*)d_out;

  const int ND = in_sizes[0];
  const int N  = ND / DD;
  const int E  = in_sizes[2] / 2;
  const int L  = in_sizes[1] / ND;

  const int nr  = divup(N, NRG);                 // ranges (196 @ N=100K)
  const int per = divup(E, BB);                  // edges per bin block
  const int cap = (per / nr) * 3 + 64;           // sub-buffer capacity (~3x mean)

  char* p = (char*)d_ws;
  auto alloc = [&](size_t bytes) -> void* {
    void* r = (void*)p;
    p += ((bytes + 255) / 256) * 256;
    return r;
  };
  auto a256 = [](size_t b) -> size_t { return ((b + 255) / 256) * 256; };

  int*      offsets = (int*)alloc((size_t)(N + 1) * 4);
  int*      bsum    = (int*)alloc(128 * 4);
  int*      bpre    = (int*)alloc(128 * 4);
  float*    dinv    = (float*)alloc((size_t)N * 4);
  int*      colcnt  = (int*)alloc((size_t)2 * N * 4);      // colcnt | rowcnt
  int*      rowcnt  = colcnt + N;
  int*      cntc    = (int*)alloc((size_t)BB * nr * 4);
  int*      cntr    = (int*)alloc((size_t)BB * nr * 4);
  int*      csr_src = (int*)alloc((size_t)E * 4);
  __half2*  XH      = (__half2*)alloc((size_t)ND * 4);     // (x,h) fp16 pairs
  _Float16* Bg      = (_Float16*)alloc((size_t)L * 24576 * 2);
  _Float16* Bo      = (_Float16*)alloc((size_t)L * 4096 * 2);
  float*    biasg   = (float*)alloc((size_t)L * 192 * 4);

  // overlay: {bufc|bufr} (CSR build) reuses {AXAH|Arh|zb|t1b|rhb} (layer loop)
  size_t bufc_b  = a256((size_t)BB * nr * cap * 4);
  size_t bufr_b  = a256((size_t)BB * nr * cap * 2);
  size_t axah_b  = a256((size_t)N * 128 * 2);
  size_t nd2_b   = a256((size_t)ND * 2);
  size_t ov_b    = axah_b + 4 * nd2_b;
  if (bufc_b + bufr_b > ov_b) ov_b = bufc_b + bufr_b;
  char* ov = (char*)alloc(ov_b);
  unsigned int*   bufc = (unsigned int*)ov;
  unsigned short* bufr = (unsigned short*)(ov + bufc_b);
  _Float16* AXAH = (_Float16*)ov;
  _Float16* Arh  = (_Float16*)(ov + axah_b);
  _Float16* zb   = (_Float16*)(ov + axah_b + nd2_b);
  _Float16* t1b  = (_Float16*)(ov + axah_b + 2 * nd2_b);
  _Float16* rhb  = (_Float16*)(ov + axah_b + 3 * nd2_b);

  // --- CSR build: LDS-cursor binning, zero global atomics ---
  bin_k<<<BB, 256, 2 * nr * 4, stream>>>(edg, E, per, nr, cap, bufc, bufr, cntc, cntr);
  cnt2_k<<<nr, 256, 0, stream>>>(bufc, bufr, cntc, cntr, BB, nr, cap, colcnt, rowcnt, N);
  const int NB = divup(N, CHUNK);
  scan1_k<<<NB, 256, 0, stream>>>(colcnt, rowcnt, dinv, bsum, N);
  scan2_k<<<1, 128, 0, stream>>>(bsum, bpre, NB);
  scan3_k<<<NB, 256, 0, stream>>>(colcnt, bpre, offsets, N);
  scat_k<<<nr, 256, 0, stream>>>(bufc, cntc, BB, nr, cap, offsets, csr_src, N);

  pack0_k<<<divup(ND, 256), 256, 0, stream>>>(inp, h, XH, ND);
  {
    const int PER = 24576 + 4096 + 192;
    packb_k<<<divup(L * PER, 256), 256, 0, stream>>>(
        Wxz, Whz, Wxr, Whr, Wxh, Whh,
        bxz, bhz, bxr, bhr, bxh, bhh, Bg, Bo, biasg, L);
  }

  const int aggBlocks = divup(N, 4);     // 4 waves (nodes) per 256-thread block
  const int mBlocks   = divup(N, 128);   // 4 waves x 32 nodes per block

  for (int l = 0; l < L; l++){
    const float* Hh = h + (size_t)l * ND;
    agg2_k<<<aggBlocks, 256, 0, stream>>>(XH, offsets, csr_src, dinv, AXAH, N);
    gatem_k<<<mBlocks, 256, 0, stream>>>(AXAH, Hh,
        Bg + (size_t)l * 24576, biasg + (size_t)l * 192, zb, rhb, t1b, N);
    agg1_k<<<aggBlocks, 256, 0, stream>>>(rhb, offsets, csr_src, dinv, Arh, N);
    const int doPack = (l + 1 < L);
    outm_k<<<mBlocks, 256, 0, stream>>>(Arh, t1b, zb, Hh,
        Bo + (size_t)l * 4096,
        out + (size_t)l * ND, out + (size_t)L * ND + (size_t)l * ND,
        h + (size_t)(l + 1 < L ? l + 1 : l) * ND, XH, doPack, N);
  }
}